// Round 12
// baseline (123.857 us; speedup 1.0000x reference)
//
#include <hip/hip_runtime.h>

#define N_NODES 50000
#define N_EDGES 800000
#define IN_DIM 128
#define OUT_DIM 128
#define N_HEADS 4
#define HEAD_DIM 32
#define LN_EPS 1e-5f

// ws layout (f32-element offsets)
#define WS_HB    0          // 3,200,000 f32 slots = 6.4M ushort (h in bf16)
#define WS_ASRC  3200000    // 200000 f32
#define WS_ADST  3400000    // 200000 f32
#define WS_ETAB  3600000    // 16 f32
#define WS_DEG   3600016    // 50000 int (zeroed by zero_kernel each call)
#define WS_AVTAB 3650016    // 2048 ushort = 512 f32 slots (cols>=8 never read)
#define WS_OFFS  3650528    // 50000 int (exclusive scan)
#define WS_PARTS 3700528    // 64 int
#define WS_EPACK 3700592    // 800016 u32 (src | etype<<16, sorted by dst; +16 pad)
#define WS_RANK  4500608    // 800000 int (edge rank within dst bucket)

#define SCAN_BLOCKS 49      // ceil(50000/1024)

typedef __bf16 bf16x8 __attribute__((ext_vector_type(8)));
typedef float  f32x4  __attribute__((ext_vector_type(4)));

__device__ __forceinline__ unsigned short f2bf(float f) {
    unsigned int u = __float_as_uint(f);
    u += 0x7FFF + ((u >> 16) & 1);          // round-to-nearest-even
    return (unsigned short)(u >> 16);
}
#define BFLO(u) __uint_as_float((unsigned int)(u) << 16)
#define BFHI(u) __uint_as_float((unsigned int)(u) & 0xFFFF0000u)
#define LRELU(c) ((c) > 0.f ? (c) : 0.2f * (c))

// ---------------- zero deg -------------------------------------------------
__global__ __launch_bounds__(256) void zero_kernel(int4* __restrict__ p)
{
    int i = blockIdx.x * 256 + threadIdx.x;
    if (i < N_NODES / 4) p[i] = make_int4(0, 0, 0, 0);
}

// ---------------- count (stores rank!) + prep (etab + av table) ------------
__global__ __launch_bounds__(256) void count_prep_kernel(
    const int* __restrict__ dsts, int* __restrict__ deg, int* __restrict__ rank,
    const float* __restrict__ W, const float* __restrict__ a_src,
    const float* __restrict__ a_dst, const float* __restrict__ edge_embed,
    const float* __restrict__ a_edge, float* __restrict__ etab,
    unsigned short* __restrict__ avtab)
{
    int gid = blockIdx.x * 256 + threadIdx.x;
    if (gid < 12) {
        int t = gid >> 2, hh = gid & 3;
        float s = 0.f;
        for (int k = 0; k < 16; ++k) s += edge_embed[t * 16 + k] * a_edge[hh * 16 + k];
        etab[t * 4 + hh] = s;
    }
    if (gid < 1024) {
        int c8 = gid & 7, k = gid >> 3;
        int hh = c8 & 3;
        const float* av = (c8 < 4) ? a_src : a_dst;
        float s = 0.f;
        #pragma unroll 8
        for (int dd = 0; dd < 32; ++dd)
            s += W[(hh * 32 + dd) * 128 + k] * av[hh * 32 + dd];
        int kblk = k >> 5, g = (k & 31) >> 3, j = k & 7;
        avtab[((kblk * 64) + g * 16 + c8) * 8 + j] = f2bf(s);
    }
    if (gid < N_EDGES) rank[gid] = atomicAdd(&deg[dsts[gid]], 1);
}

// ---------------- K1: MFMA GEMM  h(bf16) = x @ W^T  + alpha ---------------
__global__ __launch_bounds__(256) void gemm_mfma_kernel(
    const float* __restrict__ x, const float* __restrict__ W,
    const unsigned short* __restrict__ avtab,
    unsigned short* __restrict__ hb,
    float* __restrict__ alpha_src, float* __restrict__ alpha_dst)
{
    __shared__ bf16x8 wlds[2048];   // 32 KB
    int tid = threadIdx.x;
    for (int f = tid; f < 2048; f += 256) {
        int ct = f >> 8, kb = (f >> 6) & 3, ln = f & 63;
        int d = ct * 16 + (ln & 15);
        int kbase = kb * 32 + ((ln >> 4) << 3);
        const float* wp = W + d * 128 + kbase;
        float4 w0 = *(const float4*)wp;
        float4 w1 = *(const float4*)(wp + 4);
        bf16x8 v;
        v[0] = (__bf16)w0.x; v[1] = (__bf16)w0.y; v[2] = (__bf16)w0.z; v[3] = (__bf16)w0.w;
        v[4] = (__bf16)w1.x; v[5] = (__bf16)w1.y; v[6] = (__bf16)w1.z; v[7] = (__bf16)w1.w;
        wlds[f] = v;
    }
    int lane = tid & 63, wid = tid >> 6;
    bf16x8 avf[4];
    const bf16x8* avp = (const bf16x8*)avtab;
    #pragma unroll
    for (int kb = 0; kb < 4; ++kb) avf[kb] = avp[kb * 64 + lane];
    __syncthreads();

    int r = lane & 15, g = lane >> 4;
    for (int tile = blockIdx.x * 4 + wid; tile < N_NODES / 16; tile += gridDim.x * 4) {
        const float* xp = x + ((size_t)tile * 16 + r) * 128 + g * 8;
        bf16x8 af[4];
        #pragma unroll
        for (int kb = 0; kb < 4; ++kb) {
            float4 x0 = *(const float4*)(xp + kb * 32);
            float4 x1 = *(const float4*)(xp + kb * 32 + 4);
            bf16x8 v;
            v[0] = (__bf16)x0.x; v[1] = (__bf16)x0.y; v[2] = (__bf16)x0.z; v[3] = (__bf16)x0.w;
            v[4] = (__bf16)x1.x; v[5] = (__bf16)x1.y; v[6] = (__bf16)x1.z; v[7] = (__bf16)x1.w;
            af[kb] = v;
        }
        // alpha: [16 rows x 8 cols] (cols 0-3 src heads, 4-7 dst heads)
        f32x4 aacc = {0.f, 0.f, 0.f, 0.f};
        #pragma unroll
        for (int kb = 0; kb < 4; ++kb)
            aacc = __builtin_amdgcn_mfma_f32_16x16x32_bf16(af[kb], avf[kb], aacc, 0, 0, 0);

        int orow = tile * 16 + g * 4;   // C/D: row = g*4+q, col = ct*16+r
        #pragma unroll
        for (int ct = 0; ct < 8; ++ct) {
            f32x4 acc = {0.f, 0.f, 0.f, 0.f};
            #pragma unroll
            for (int kb = 0; kb < 4; ++kb)
                acc = __builtin_amdgcn_mfma_f32_16x16x32_bf16(af[kb], wlds[(ct * 4 + kb) * 64 + lane], acc, 0, 0, 0);
            #pragma unroll
            for (int q = 0; q < 4; ++q)
                hb[(size_t)(orow + q) * 128 + ct * 16 + r] = f2bf(acc[q]);
        }
        if (r < 8) {
            float* ap = (r < 4) ? (alpha_src + (r & 3)) : (alpha_dst + (r & 3));
            #pragma unroll
            for (int q = 0; q < 4; ++q)
                ap[(size_t)(orow + q) * 4] = aacc[q];
        }
    }
}

// ---------------- scan: per-tile exclusive + parts -------------------------
__global__ __launch_bounds__(1024) void scan_part_kernel(
    const int* __restrict__ deg, int* __restrict__ offs, int* __restrict__ parts)
{
    __shared__ int wsum[16];
    int i = blockIdx.x * 1024 + threadIdx.x;
    int lane = threadIdx.x & 63;
    int wid  = threadIdx.x >> 6;
    int v = (i < N_NODES) ? deg[i] : 0;
    int xinc = v;
    #pragma unroll
    for (int d = 1; d < 64; d <<= 1) {
        int y = __shfl_up(xinc, d);
        if (lane >= d) xinc += y;
    }
    if (lane == 63) wsum[wid] = xinc;
    __syncthreads();
    if (wid == 0) {
        int sv = (lane < 16) ? wsum[lane] : 0;
        #pragma unroll
        for (int d = 1; d < 16; d <<= 1) {
            int y = __shfl_up(sv, d);
            if (lane >= d) sv += y;
        }
        if (lane < 16) wsum[lane] = sv;
    }
    __syncthreads();
    int woff = (wid > 0) ? wsum[wid - 1] : 0;
    if (i < N_NODES) offs[i] = woff + xinc - v;   // tile-local exclusive
    if (threadIdx.x == 0) parts[blockIdx.x] = wsum[15];
}

// each block sums parts[0..bid-1] itself (fuses scan_tops + scan_add)
__global__ __launch_bounds__(1024) void scan_add_kernel(
    int* __restrict__ offs, const int* __restrict__ parts)
{
    __shared__ int pre_s;
    if (threadIdx.x < 64) {
        int v = ((int)threadIdx.x < (int)blockIdx.x) ? parts[threadIdx.x] : 0;
        #pragma unroll
        for (int off = 32; off >= 1; off >>= 1) v += __shfl_xor(v, off);
        if (threadIdx.x == 0) pre_s = v;
    }
    __syncthreads();
    int i = blockIdx.x * 1024 + threadIdx.x;
    if (i < N_NODES) offs[i] += pre_s;
}

// fill: NO atomics — rank precomputed in count_prep
__global__ void fill_kernel(const int* __restrict__ srcs, const int* __restrict__ dsts,
                            const int* __restrict__ etype, const int* __restrict__ rank,
                            const int* __restrict__ offs, unsigned int* __restrict__ epack)
{
    int e = blockIdx.x * 256 + threadIdx.x;
    if (e < N_EDGES) {
        int d = dsts[e];
        int p = offs[d] + rank[e];
        epack[p] = (unsigned int)srcs[e] | ((unsigned int)etype[e] << 16);
    }
}

// ---------------- K5: phase-split softmax+aggregate+residual+LayerNorm ----
// One node per 32-lane half; lane owns 4 dims (head = l5>>3).
__global__ __launch_bounds__(256) void aggregate_kernel(
    const unsigned short* __restrict__ hb, const float* __restrict__ alpha_src,
    const float* __restrict__ alpha_dst, const float* __restrict__ etab,
    const unsigned int* __restrict__ epack, const int* __restrict__ offs,
    const float* __restrict__ gamma, const float* __restrict__ beta,
    float* __restrict__ out)
{
    int lane = threadIdx.x & 63;
    int wid  = threadIdx.x >> 6;
    int half = lane >> 5;              // two nodes per wave
    int l5   = lane & 31;
    int n = blockIdx.x * 8 + wid * 2 + half;

    int e0 = offs[n];                         // exclusive scan
    int e1 = (n == N_NODES - 1) ? N_EDGES : offs[n + 1];
    int dg = e1 - e0;

    int headL = l5 >> 3;         // head of this lane's 4 dims

    float4 adv = *(const float4*)(alpha_dst + (size_t)n * 4);
    const float4* etabv = (const float4*)etab;

    float4 s4 = make_float4(0.f, 0.f, 0.f, 0.f);
    float acc0 = 0.f, acc1 = 0.f, acc2 = 0.f, acc3 = 0.f;

    const unsigned int* ep = epack + e0;
    int nb = (dg + 31) >> 5;
    for (int b = 0; b < nb; ++b) {
        int jb = b << 5;
        int myj = jb + l5;
        bool valid = myj < dg;
        // ---- phase 1: coalesced epack + batched alpha gather + weights ----
        unsigned int p = 0;
        if (valid) p = ep[myj];
        int sim = p & 0xFFFF;
        int t   = p >> 16;
        float4 al = *(const float4*)(alpha_src + (size_t)sim * 4);
        float4 et = etabv[t];
        float w0 = valid ? __expf(LRELU(al.x + adv.x + et.x)) : 0.f;
        float w1 = valid ? __expf(LRELU(al.y + adv.y + et.y)) : 0.f;
        float w2 = valid ? __expf(LRELU(al.z + adv.z + et.z)) : 0.f;
        float w3 = valid ? __expf(LRELU(al.w + adv.w + et.w)) : 0.f;
        s4.x += w0; s4.y += w1; s4.z += w2; s4.w += w3;
        int up0 = (int)(((unsigned)f2bf(w1) << 16) | f2bf(w0));
        int up1 = (int)(((unsigned)f2bf(w3) << 16) | f2bf(w2));

        // ---- phase 2: all 32 lanes gather each edge's h row (8B/lane) ----
        int cnt = (dg - jb < 32) ? (dg - jb) : 32;
        #pragma unroll 4
        for (int j = 0; j < cnt; ++j) {
            int sj = __shfl(sim, j, 32);
            int u0 = __shfl(up0, j, 32);
            int u1 = __shfl(up1, j, 32);
            unsigned int pick = (unsigned int)((headL & 2) ? u1 : u0);
            float w = (headL & 1) ? BFHI(pick) : BFLO(pick);
            uint2 hv = *(const uint2*)(hb + ((size_t)sj << 7) + (l5 << 2));
            acc0 += w * BFLO(hv.x); acc1 += w * BFHI(hv.x);
            acc2 += w * BFLO(hv.y); acc3 += w * BFHI(hv.y);
        }
    }

    // denominator: reduce s4 across the 32-lane half, pick own head
    #pragma unroll
    for (int off = 16; off >= 1; off >>= 1) {
        s4.x += __shfl_xor(s4.x, off);
        s4.y += __shfl_xor(s4.y, off);
        s4.z += __shfl_xor(s4.z, off);
        s4.w += __shfl_xor(s4.w, off);
    }
    float s = (headL & 2) ? ((headL & 1) ? s4.w : s4.z) : ((headL & 1) ? s4.y : s4.x);
    float rs = 1.0f / (s + 1e-10f);

    // ---- epilogue: normalize + residual + LayerNorm (4 dims per lane) ----
    uint2 rv = *(const uint2*)(hb + ((size_t)n << 7) + (l5 << 2));
    float o0 = acc0 * rs + BFLO(rv.x);
    float o1 = acc1 * rs + BFHI(rv.x);
    float o2 = acc2 * rs + BFLO(rv.y);
    float o3 = acc3 * rs + BFHI(rv.y);

    float lsum = o0 + o1 + o2 + o3;
    #pragma unroll
    for (int off = 16; off >= 1; off >>= 1) lsum += __shfl_xor(lsum, off);
    float mean = lsum * (1.0f / 128.0f);
    float d0 = o0 - mean, d1 = o1 - mean, d2 = o2 - mean, d3 = o3 - mean;
    float vs = d0 * d0 + d1 * d1 + d2 * d2 + d3 * d3;
    #pragma unroll
    for (int off = 16; off >= 1; off >>= 1) vs += __shfl_xor(vs, off);
    float inv = rsqrtf(vs * (1.0f / 128.0f) + LN_EPS);

    float4 gv = *(const float4*)(gamma + l5 * 4);
    float4 bv = *(const float4*)(beta  + l5 * 4);
    float4 wv;
    wv.x = d0 * inv * gv.x + bv.x;
    wv.y = d1 * inv * gv.y + bv.y;
    wv.z = d2 * inv * gv.z + bv.z;
    wv.w = d3 * inv * gv.w + bv.w;
    *(float4*)(out + (size_t)n * OUT_DIM + l5 * 4) = wv;
}

// ---------------------------------------------------------------------------
extern "C" void kernel_launch(void* const* d_in, const int* in_sizes, int n_in,
                              void* d_out, int out_size, void* d_ws, size_t ws_size,
                              hipStream_t stream)
{
    const float* x          = (const float*)d_in[0];
    const int*   edge_index = (const int*)d_in[1];
    const int*   etype      = (const int*)d_in[2];
    const float* W          = (const float*)d_in[3];
    const float* a_src      = (const float*)d_in[4];
    const float* a_dst      = (const float*)d_in[5];
    const float* a_edge     = (const float*)d_in[6];
    const float* edge_embed = (const float*)d_in[7];
    const float* gamma      = (const float*)d_in[8];
    const float* beta       = (const float*)d_in[9];

    float* ws = (float*)d_ws;
    unsigned short* hb = (unsigned short*)(ws + WS_HB);
    float* asrc = ws + WS_ASRC;
    float* adst = ws + WS_ADST;
    float* etab = ws + WS_ETAB;
    int*   deg  = (int*)d_ws + WS_DEG;
    unsigned short* avtab = (unsigned short*)((int*)d_ws + WS_AVTAB);
    int*   offs = (int*)d_ws + WS_OFFS;
    int*   parts= (int*)d_ws + WS_PARTS;
    unsigned int* epack = (unsigned int*)d_ws + WS_EPACK;
    int*   rank = (int*)d_ws + WS_RANK;

    const int* srcs = edge_index;
    const int* dsts = edge_index + N_EDGES;

    zero_kernel<<<(N_NODES / 4 + 255) / 256, 256, 0, stream>>>((int4*)deg);
    count_prep_kernel<<<(N_EDGES + 255) / 256, 256, 0, stream>>>(
        dsts, deg, rank, W, a_src, a_dst, edge_embed, a_edge, etab, avtab);
    gemm_mfma_kernel<<<512, 256, 0, stream>>>(x, W, avtab, hb, asrc, adst);
    scan_part_kernel<<<SCAN_BLOCKS, 1024, 0, stream>>>(deg, offs, parts);
    scan_add_kernel<<<SCAN_BLOCKS, 1024, 0, stream>>>(offs, parts);
    fill_kernel<<<(N_EDGES + 255) / 256, 256, 0, stream>>>(srcs, dsts, etype, rank, offs, epack);
    aggregate_kernel<<<(N_NODES + 7) / 8, 256, 0, stream>>>(
        hb, asrc, adst, etab, epack, offs, gamma, beta, (float*)d_out);
}

// Round 13
// 110.590 us; speedup vs baseline: 1.1200x; 1.1200x over previous
//
#include <hip/hip_runtime.h>

#define N_NODES 50000
#define N_EDGES 800000
#define IN_DIM 128
#define OUT_DIM 128
#define N_HEADS 4
#define HEAD_DIM 32
#define LN_EPS 1e-5f

// ws layout (f32-element offsets)
#define WS_HB    0          // 3,200,000 f32 slots = 6.4M ushort (h in bf16)
#define WS_ASRC  3200000    // 200000 f32
#define WS_ADST  3400000    // 200000 f32
#define WS_ETAB  3600000    // 16 f32
#define WS_DEG   3600016    // 50000 int (zeroed by prep_zero each call)
#define WS_AVTAB 3650016    // 2048 ushort = 512 f32 slots (cols>=8 never read)
#define WS_OFFS  3650528    // 50000 int (exclusive scan)
#define WS_PARTS 3700528    // 64 int
#define WS_EPACK 3700592    // 800016 u32 (src | etype<<16, sorted by dst; +16 pad)
#define WS_RANK  4500608    // 800000 int (edge rank within dst bucket)

#define SCAN_BLOCKS 49      // ceil(50000/1024)
#define GEMM_BLOCKS 512
#define COUNT_BLOCKS 3125   // ceil(800000/256)

typedef __bf16 bf16x8 __attribute__((ext_vector_type(8)));
typedef float  f32x4  __attribute__((ext_vector_type(4)));

__device__ __forceinline__ unsigned short f2bf(float f) {
    unsigned int u = __float_as_uint(f);
    u += 0x7FFF + ((u >> 16) & 1);          // round-to-nearest-even
    return (unsigned short)(u >> 16);
}
#define BFLO(u) __uint_as_float((unsigned int)(u) << 16)
#define BFHI(u) __uint_as_float((unsigned int)(u) & 0xFFFF0000u)
#define LRELU(c) ((c) > 0.f ? (c) : 0.2f * (c))

// ---------------- prep_zero: zero deg + build etab/avtab -------------------
// (prep must finish BEFORE the fused gemm+count kernel, since gemm reads avtab)
__global__ __launch_bounds__(256) void prep_zero_kernel(
    int4* __restrict__ degv,
    const float* __restrict__ W, const float* __restrict__ a_src,
    const float* __restrict__ a_dst, const float* __restrict__ edge_embed,
    const float* __restrict__ a_edge, float* __restrict__ etab,
    unsigned short* __restrict__ avtab)
{
    int gid = blockIdx.x * 256 + threadIdx.x;
    if (gid < N_NODES / 4) degv[gid] = make_int4(0, 0, 0, 0);
    if (gid < 12) {
        int t = gid >> 2, hh = gid & 3;
        float s = 0.f;
        for (int k = 0; k < 16; ++k) s += edge_embed[t * 16 + k] * a_edge[hh * 16 + k];
        etab[t * 4 + hh] = s;
    }
    if (gid < 1024) {
        int c8 = gid & 7, k = gid >> 3;
        int hh = c8 & 3;
        const float* av = (c8 < 4) ? a_src : a_dst;
        float s = 0.f;
        #pragma unroll 8
        for (int dd = 0; dd < 32; ++dd)
            s += W[(hh * 32 + dd) * 128 + k] * av[hh * 32 + dd];
        int kblk = k >> 5, g = (k & 31) >> 3, j = k & 7;
        avtab[((kblk * 64) + g * 16 + c8) * 8 + j] = f2bf(s);
    }
}

// ---------------- fused: MFMA GEMM (blocks 0..511) + count (blocks 512..) --
// Independent work co-scheduled: atomic latency hides under MFMA.
__global__ __launch_bounds__(256) void gemm_count_kernel(
    const float* __restrict__ x, const float* __restrict__ W,
    const unsigned short* __restrict__ avtab,
    unsigned short* __restrict__ hb,
    float* __restrict__ alpha_src, float* __restrict__ alpha_dst,
    const int* __restrict__ dsts, int* __restrict__ deg, int* __restrict__ rank)
{
    __shared__ bf16x8 wlds[2048];   // 32 KB (gemm path only)
    int tid = threadIdx.x;

    if (blockIdx.x >= GEMM_BLOCKS) {
        // ---------------- count path ----------------
        int gid = (blockIdx.x - GEMM_BLOCKS) * 256 + tid;
        if (gid < N_EDGES) rank[gid] = atomicAdd(&deg[dsts[gid]], 1);
        return;
    }

    // ---------------- gemm path ----------------
    for (int f = tid; f < 2048; f += 256) {
        int ct = f >> 8, kb = (f >> 6) & 3, ln = f & 63;
        int d = ct * 16 + (ln & 15);
        int kbase = kb * 32 + ((ln >> 4) << 3);
        const float* wp = W + d * 128 + kbase;
        float4 w0 = *(const float4*)wp;
        float4 w1 = *(const float4*)(wp + 4);
        bf16x8 v;
        v[0] = (__bf16)w0.x; v[1] = (__bf16)w0.y; v[2] = (__bf16)w0.z; v[3] = (__bf16)w0.w;
        v[4] = (__bf16)w1.x; v[5] = (__bf16)w1.y; v[6] = (__bf16)w1.z; v[7] = (__bf16)w1.w;
        wlds[f] = v;
    }
    int lane = tid & 63, wid = tid >> 6;
    bf16x8 avf[4];
    const bf16x8* avp = (const bf16x8*)avtab;
    #pragma unroll
    for (int kb = 0; kb < 4; ++kb) avf[kb] = avp[kb * 64 + lane];
    __syncthreads();

    int r = lane & 15, g = lane >> 4;
    for (int tile = blockIdx.x * 4 + wid; tile < N_NODES / 16; tile += GEMM_BLOCKS * 4) {
        const float* xp = x + ((size_t)tile * 16 + r) * 128 + g * 8;
        bf16x8 af[4];
        #pragma unroll
        for (int kb = 0; kb < 4; ++kb) {
            float4 x0 = *(const float4*)(xp + kb * 32);
            float4 x1 = *(const float4*)(xp + kb * 32 + 4);
            bf16x8 v;
            v[0] = (__bf16)x0.x; v[1] = (__bf16)x0.y; v[2] = (__bf16)x0.z; v[3] = (__bf16)x0.w;
            v[4] = (__bf16)x1.x; v[5] = (__bf16)x1.y; v[6] = (__bf16)x1.z; v[7] = (__bf16)x1.w;
            af[kb] = v;
        }
        // alpha: [16 rows x 8 cols] (cols 0-3 src heads, 4-7 dst heads)
        f32x4 aacc = {0.f, 0.f, 0.f, 0.f};
        #pragma unroll
        for (int kb = 0; kb < 4; ++kb)
            aacc = __builtin_amdgcn_mfma_f32_16x16x32_bf16(af[kb], avf[kb], aacc, 0, 0, 0);

        int orow = tile * 16 + g * 4;   // C/D: row = g*4+q, col = ct*16+r
        #pragma unroll
        for (int ct = 0; ct < 8; ++ct) {
            f32x4 acc = {0.f, 0.f, 0.f, 0.f};
            #pragma unroll
            for (int kb = 0; kb < 4; ++kb)
                acc = __builtin_amdgcn_mfma_f32_16x16x32_bf16(af[kb], wlds[(ct * 4 + kb) * 64 + lane], acc, 0, 0, 0);
            #pragma unroll
            for (int q = 0; q < 4; ++q)
                hb[(size_t)(orow + q) * 128 + ct * 16 + r] = f2bf(acc[q]);
        }
        if (r < 8) {
            float* ap = (r < 4) ? (alpha_src + (r & 3)) : (alpha_dst + (r & 3));
            #pragma unroll
            for (int q = 0; q < 4; ++q)
                ap[(size_t)(orow + q) * 4] = aacc[q];
        }
    }
}

// ---------------- scan: per-tile exclusive + parts -------------------------
__global__ __launch_bounds__(1024) void scan_part_kernel(
    const int* __restrict__ deg, int* __restrict__ offs, int* __restrict__ parts)
{
    __shared__ int wsum[16];
    int i = blockIdx.x * 1024 + threadIdx.x;
    int lane = threadIdx.x & 63;
    int wid  = threadIdx.x >> 6;
    int v = (i < N_NODES) ? deg[i] : 0;
    int xinc = v;
    #pragma unroll
    for (int d = 1; d < 64; d <<= 1) {
        int y = __shfl_up(xinc, d);
        if (lane >= d) xinc += y;
    }
    if (lane == 63) wsum[wid] = xinc;
    __syncthreads();
    if (wid == 0) {
        int sv = (lane < 16) ? wsum[lane] : 0;
        #pragma unroll
        for (int d = 1; d < 16; d <<= 1) {
            int y = __shfl_up(sv, d);
            if (lane >= d) sv += y;
        }
        if (lane < 16) wsum[lane] = sv;
    }
    __syncthreads();
    int woff = (wid > 0) ? wsum[wid - 1] : 0;
    if (i < N_NODES) offs[i] = woff + xinc - v;   // tile-local exclusive
    if (threadIdx.x == 0) parts[blockIdx.x] = wsum[15];
}

// each block sums parts[0..bid-1] itself (fuses scan_tops + scan_add)
__global__ __launch_bounds__(1024) void scan_add_kernel(
    int* __restrict__ offs, const int* __restrict__ parts)
{
    __shared__ int pre_s;
    if (threadIdx.x < 64) {
        int v = ((int)threadIdx.x < (int)blockIdx.x) ? parts[threadIdx.x] : 0;
        #pragma unroll
        for (int off = 32; off >= 1; off >>= 1) v += __shfl_xor(v, off);
        if (threadIdx.x == 0) pre_s = v;
    }
    __syncthreads();
    int i = blockIdx.x * 1024 + threadIdx.x;
    if (i < N_NODES) offs[i] += pre_s;
}

// fill: NO atomics — rank precomputed in gemm_count
__global__ void fill_kernel(const int* __restrict__ srcs, const int* __restrict__ dsts,
                            const int* __restrict__ etype, const int* __restrict__ rank,
                            const int* __restrict__ offs, unsigned int* __restrict__ epack)
{
    int e = blockIdx.x * 256 + threadIdx.x;
    if (e < N_EDGES) {
        int d = dsts[e];
        int p = offs[d] + rank[e];
        epack[p] = (unsigned int)srcs[e] | ((unsigned int)etype[e] << 16);
    }
}

// ---------------- K5: fused softmax+aggregate+residual+LayerNorm ----------
__global__ __launch_bounds__(256) void aggregate_kernel(
    const unsigned short* __restrict__ hb, const float* __restrict__ alpha_src,
    const float* __restrict__ alpha_dst, const float* __restrict__ etab,
    const unsigned int* __restrict__ epack, const int* __restrict__ offs,
    const float* __restrict__ gamma, const float* __restrict__ beta,
    float* __restrict__ out)
{
    int lane = threadIdx.x & 63;
    int wid  = threadIdx.x >> 6;
    int half = lane >> 5;              // two nodes per wave
    int l5   = lane & 31;
    int n = blockIdx.x * 8 + wid * 2 + half;
    if (n >= N_NODES) return;

    int e0 = offs[n];                         // exclusive scan
    int e1 = (n == N_NODES - 1) ? N_EDGES : offs[n + 1];
    int dg = e1 - e0;

    int g  = l5 >> 3;            // edge group 0..3 (stride-4 over edges)
    int sl = l5 & 7;             // dims sl*16 .. sl*16+15
    int headL = sl >> 1;

    float ad_h = alpha_dst[(size_t)n * 4 + headL];
    float et0 = etab[0 * 4 + headL];
    float et1 = etab[1 * 4 + headL];
    float et2 = etab[2 * 4 + headL];

    float s = 0.f;
    float acc[16];
    #pragma unroll
    for (int k = 0; k < 16; ++k) acc[k] = 0.f;

    const unsigned int* ep = epack + e0;
    for (int j = g; j < dg; j += 4) {
        unsigned int p = ep[j];
        int si = p & 0xFFFF;
        int t  = p >> 16;
        float asv = alpha_src[(size_t)si * 4 + headL];
        const uint4* hp = (const uint4*)(hb + ((size_t)si << 7) + (sl << 4));
        uint4 hA = hp[0];
        uint4 hB = hp[1];
        float ev = (t == 0) ? et0 : ((t == 1) ? et1 : et2);
        float c = LRELU(asv + ad_h + ev);
        float w = __expf(c);
        s += w;
        acc[0]  += w * BFLO(hA.x); acc[1]  += w * BFHI(hA.x);
        acc[2]  += w * BFLO(hA.y); acc[3]  += w * BFHI(hA.y);
        acc[4]  += w * BFLO(hA.z); acc[5]  += w * BFHI(hA.z);
        acc[6]  += w * BFLO(hA.w); acc[7]  += w * BFHI(hA.w);
        acc[8]  += w * BFLO(hB.x); acc[9]  += w * BFHI(hB.x);
        acc[10] += w * BFLO(hB.y); acc[11] += w * BFHI(hB.y);
        acc[12] += w * BFLO(hB.z); acc[13] += w * BFHI(hB.z);
        acc[14] += w * BFLO(hB.w); acc[15] += w * BFHI(hB.w);
    }

    // combine the 4 edge-groups
    #pragma unroll
    for (int k = 0; k < 16; ++k) {
        acc[k] += __shfl_xor(acc[k], 8);
        acc[k] += __shfl_xor(acc[k], 16);
    }
    s += __shfl_xor(s, 8);
    s += __shfl_xor(s, 16);
    float rs = 1.0f / (s + 1e-10f);

    // ---- epilogue: normalize + residual + LayerNorm ----
    const uint4* rp = (const uint4*)(hb + ((size_t)n << 7) + (sl << 4));
    uint4 r0 = rp[0];
    uint4 r1 = rp[1];
    float o[16];
    o[0]  = acc[0]  * rs + BFLO(r0.x); o[1]  = acc[1]  * rs + BFHI(r0.x);
    o[2]  = acc[2]  * rs + BFLO(r0.y); o[3]  = acc[3]  * rs + BFHI(r0.y);
    o[4]  = acc[4]  * rs + BFLO(r0.z); o[5]  = acc[5]  * rs + BFHI(r0.z);
    o[6]  = acc[6]  * rs + BFLO(r0.w); o[7]  = acc[7]  * rs + BFHI(r0.w);
    o[8]  = acc[8]  * rs + BFLO(r1.x); o[9]  = acc[9]  * rs + BFHI(r1.x);
    o[10] = acc[10] * rs + BFLO(r1.y); o[11] = acc[11] * rs + BFHI(r1.y);
    o[12] = acc[12] * rs + BFLO(r1.z); o[13] = acc[13] * rs + BFHI(r1.z);
    o[14] = acc[14] * rs + BFLO(r1.w); o[15] = acc[15] * rs + BFHI(r1.w);

    float lsum = 0.f;
    #pragma unroll
    for (int k = 0; k < 16; ++k) lsum += o[k];
    #pragma unroll
    for (int off = 4; off >= 1; off >>= 1) lsum += __shfl_xor(lsum, off);
    float mean = lsum * (1.0f / 128.0f);
    float vs = 0.f;
    #pragma unroll
    for (int k = 0; k < 16; ++k) { float d = o[k] - mean; vs += d * d; }
    #pragma unroll
    for (int off = 4; off >= 1; off >>= 1) vs += __shfl_xor(vs, off);
    float inv = rsqrtf(vs * (1.0f / 128.0f) + LN_EPS);

    float4 gv = *(const float4*)(gamma + sl * 16 + g * 4);
    float4 bv = *(const float4*)(beta  + sl * 16 + g * 4);
    float4 wv;
    wv.x = (o[g * 4 + 0] - mean) * inv * gv.x + bv.x;
    wv.y = (o[g * 4 + 1] - mean) * inv * gv.y + bv.y;
    wv.z = (o[g * 4 + 2] - mean) * inv * gv.z + bv.z;
    wv.w = (o[g * 4 + 3] - mean) * inv * gv.w + bv.w;
    *(float4*)(out + (size_t)n * OUT_DIM + sl * 16 + g * 4) = wv;
}

// ---------------------------------------------------------------------------
extern "C" void kernel_launch(void* const* d_in, const int* in_sizes, int n_in,
                              void* d_out, int out_size, void* d_ws, size_t ws_size,
                              hipStream_t stream)
{
    const float* x          = (const float*)d_in[0];
    const int*   edge_index = (const int*)d_in[1];
    const int*   etype      = (const int*)d_in[2];
    const float* W          = (const float*)d_in[3];
    const float* a_src      = (const float*)d_in[4];
    const float* a_dst      = (const float*)d_in[5];
    const float* a_edge     = (const float*)d_in[6];
    const float* edge_embed = (const float*)d_in[7];
    const float* gamma      = (const float*)d_in[8];
    const float* beta       = (const float*)d_in[9];

    float* ws = (float*)d_ws;
    unsigned short* hb = (unsigned short*)(ws + WS_HB);
    float* asrc = ws + WS_ASRC;
    float* adst = ws + WS_ADST;
    float* etab = ws + WS_ETAB;
    int*   deg  = (int*)d_ws + WS_DEG;
    unsigned short* avtab = (unsigned short*)((int*)d_ws + WS_AVTAB);
    int*   offs = (int*)d_ws + WS_OFFS;
    int*   parts= (int*)d_ws + WS_PARTS;
    unsigned int* epack = (unsigned int*)d_ws + WS_EPACK;
    int*   rank = (int*)d_ws + WS_RANK;

    const int* srcs = edge_index;
    const int* dsts = edge_index + N_EDGES;

    prep_zero_kernel<<<SCAN_BLOCKS, 256, 0, stream>>>(
        (int4*)deg, W, a_src, a_dst, edge_embed, a_edge, etab, avtab);
    gemm_count_kernel<<<GEMM_BLOCKS + COUNT_BLOCKS, 256, 0, stream>>>(
        x, W, avtab, hb, asrc, adst, dsts, deg, rank);
    scan_part_kernel<<<SCAN_BLOCKS, 1024, 0, stream>>>(deg, offs, parts);
    scan_add_kernel<<<SCAN_BLOCKS, 1024, 0, stream>>>(offs, parts);
    fill_kernel<<<(N_EDGES + 255) / 256, 256, 0, stream>>>(srcs, dsts, etype, rank, offs, epack);
    aggregate_kernel<<<(N_NODES + 7) / 8, 256, 0, stream>>>(
        hb, asrc, adst, etab, epack, offs, gamma, beta, (float*)d_out);
}

// Round 14
// 108.654 us; speedup vs baseline: 1.1399x; 1.0178x over previous
//
#include <hip/hip_runtime.h>

#define N_NODES 50000
#define N_EDGES 800000
#define IN_DIM 128
#define OUT_DIM 128
#define N_HEADS 4
#define HEAD_DIM 32
#define LN_EPS 1e-5f

// ws layout (f32-element offsets)
#define WS_HB    0          // 3,200,000 f32 slots = 6.4M ushort (h in bf16)
#define WS_ASRC  3200000    // 200000 f32
#define WS_ADST  3400000    // 200000 f32
#define WS_ETAB  3600000    // 16 f32
#define WS_AVTAB 3650016    // 2048 ushort = 512 f32 slots (cols>=8 never read)
#define WS_OFFS  3650528    // 50000 int (exclusive scan)
#define WS_PARTS 3700528    // 64 int
#define WS_EPACK 3700592    // 800016 u32 (src | etype<<16, sorted by dst; +16 pad)
#define WS_RANK  4500608    // 800000 int (edge rank within dst bucket)
#define WS_DEGP  5300608    // 800000 int: deg padded, ONE counter per 64B line (d<<4)

#define SCAN_BLOCKS 49      // ceil(50000/1024)
#define GEMM_BLOCKS 512
#define COUNT_BLOCKS 3125   // ceil(800000/256)
#define PREP_BLOCKS 782     // ceil(200000 int4 / 256)

typedef __bf16 bf16x8 __attribute__((ext_vector_type(8)));
typedef float  f32x4  __attribute__((ext_vector_type(4)));

__device__ __forceinline__ unsigned short f2bf(float f) {
    unsigned int u = __float_as_uint(f);
    u += 0x7FFF + ((u >> 16) & 1);          // round-to-nearest-even
    return (unsigned short)(u >> 16);
}
#define BFLO(u) __uint_as_float((unsigned int)(u) << 16)
#define BFHI(u) __uint_as_float((unsigned int)(u) & 0xFFFF0000u)
#define LRELU(c) ((c) > 0.f ? (c) : 0.2f * (c))

// ---------------- prep_zero: zero padded deg + build etab/avtab ------------
__global__ __launch_bounds__(256) void prep_zero_kernel(
    int4* __restrict__ degv,
    const float* __restrict__ W, const float* __restrict__ a_src,
    const float* __restrict__ a_dst, const float* __restrict__ edge_embed,
    const float* __restrict__ a_edge, float* __restrict__ etab,
    unsigned short* __restrict__ avtab)
{
    int gid = blockIdx.x * 256 + threadIdx.x;
    if (gid < 200000) degv[gid] = make_int4(0, 0, 0, 0);   // 800000 ints (d<<4 stride)
    if (gid < 12) {
        int t = gid >> 2, hh = gid & 3;
        float s = 0.f;
        for (int k = 0; k < 16; ++k) s += edge_embed[t * 16 + k] * a_edge[hh * 16 + k];
        etab[t * 4 + hh] = s;
    }
    if (gid < 1024) {
        int c8 = gid & 7, k = gid >> 3;
        int hh = c8 & 3;
        const float* av = (c8 < 4) ? a_src : a_dst;
        float s = 0.f;
        #pragma unroll 8
        for (int dd = 0; dd < 32; ++dd)
            s += W[(hh * 32 + dd) * 128 + k] * av[hh * 32 + dd];
        int kblk = k >> 5, g = (k & 31) >> 3, j = k & 7;
        avtab[((kblk * 64) + g * 16 + c8) * 8 + j] = f2bf(s);
    }
}

// ---------------- fused: MFMA GEMM (blocks 0..511) + count (blocks 512..) --
__global__ __launch_bounds__(256) void gemm_count_kernel(
    const float* __restrict__ x, const float* __restrict__ W,
    const unsigned short* __restrict__ avtab,
    unsigned short* __restrict__ hb,
    float* __restrict__ alpha_src, float* __restrict__ alpha_dst,
    const int* __restrict__ dsts, int* __restrict__ degp, int* __restrict__ rank)
{
    __shared__ bf16x8 wlds[2048];   // 32 KB (gemm path only)
    int tid = threadIdx.x;

    if (blockIdx.x >= GEMM_BLOCKS) {
        // ---------------- count path: one counter per 64B line ----------------
        int gid = (blockIdx.x - GEMM_BLOCKS) * 256 + tid;
        if (gid < N_EDGES) rank[gid] = atomicAdd(&degp[dsts[gid] << 4], 1);
        return;
    }

    // ---------------- gemm path ----------------
    for (int f = tid; f < 2048; f += 256) {
        int ct = f >> 8, kb = (f >> 6) & 3, ln = f & 63;
        int d = ct * 16 + (ln & 15);
        int kbase = kb * 32 + ((ln >> 4) << 3);
        const float* wp = W + d * 128 + kbase;
        float4 w0 = *(const float4*)wp;
        float4 w1 = *(const float4*)(wp + 4);
        bf16x8 v;
        v[0] = (__bf16)w0.x; v[1] = (__bf16)w0.y; v[2] = (__bf16)w0.z; v[3] = (__bf16)w0.w;
        v[4] = (__bf16)w1.x; v[5] = (__bf16)w1.y; v[6] = (__bf16)w1.z; v[7] = (__bf16)w1.w;
        wlds[f] = v;
    }
    int lane = tid & 63, wid = tid >> 6;
    bf16x8 avf[4];
    const bf16x8* avp = (const bf16x8*)avtab;
    #pragma unroll
    for (int kb = 0; kb < 4; ++kb) avf[kb] = avp[kb * 64 + lane];
    __syncthreads();

    int r = lane & 15, g = lane >> 4;
    for (int tile = blockIdx.x * 4 + wid; tile < N_NODES / 16; tile += GEMM_BLOCKS * 4) {
        const float* xp = x + ((size_t)tile * 16 + r) * 128 + g * 8;
        bf16x8 af[4];
        #pragma unroll
        for (int kb = 0; kb < 4; ++kb) {
            float4 x0 = *(const float4*)(xp + kb * 32);
            float4 x1 = *(const float4*)(xp + kb * 32 + 4);
            bf16x8 v;
            v[0] = (__bf16)x0.x; v[1] = (__bf16)x0.y; v[2] = (__bf16)x0.z; v[3] = (__bf16)x0.w;
            v[4] = (__bf16)x1.x; v[5] = (__bf16)x1.y; v[6] = (__bf16)x1.z; v[7] = (__bf16)x1.w;
            af[kb] = v;
        }
        // alpha: [16 rows x 8 cols] (cols 0-3 src heads, 4-7 dst heads)
        f32x4 aacc = {0.f, 0.f, 0.f, 0.f};
        #pragma unroll
        for (int kb = 0; kb < 4; ++kb)
            aacc = __builtin_amdgcn_mfma_f32_16x16x32_bf16(af[kb], avf[kb], aacc, 0, 0, 0);

        int orow = tile * 16 + g * 4;   // C/D: row = g*4+q, col = ct*16+r
        #pragma unroll
        for (int ct = 0; ct < 8; ++ct) {
            f32x4 acc = {0.f, 0.f, 0.f, 0.f};
            #pragma unroll
            for (int kb = 0; kb < 4; ++kb)
                acc = __builtin_amdgcn_mfma_f32_16x16x32_bf16(af[kb], wlds[(ct * 4 + kb) * 64 + lane], acc, 0, 0, 0);
            #pragma unroll
            for (int q = 0; q < 4; ++q)
                hb[(size_t)(orow + q) * 128 + ct * 16 + r] = f2bf(acc[q]);
        }
        if (r < 8) {
            float* ap = (r < 4) ? (alpha_src + (r & 3)) : (alpha_dst + (r & 3));
            #pragma unroll
            for (int q = 0; q < 4; ++q)
                ap[(size_t)(orow + q) * 4] = aacc[q];
        }
    }
}

// ---------------- scan: per-tile exclusive + parts (reads padded deg) ------
__global__ __launch_bounds__(1024) void scan_part_kernel(
    const int* __restrict__ degp, int* __restrict__ offs, int* __restrict__ parts)
{
    __shared__ int wsum[16];
    int i = blockIdx.x * 1024 + threadIdx.x;
    int lane = threadIdx.x & 63;
    int wid  = threadIdx.x >> 6;
    int v = (i < N_NODES) ? degp[i << 4] : 0;
    int xinc = v;
    #pragma unroll
    for (int d = 1; d < 64; d <<= 1) {
        int y = __shfl_up(xinc, d);
        if (lane >= d) xinc += y;
    }
    if (lane == 63) wsum[wid] = xinc;
    __syncthreads();
    if (wid == 0) {
        int sv = (lane < 16) ? wsum[lane] : 0;
        #pragma unroll
        for (int d = 1; d < 16; d <<= 1) {
            int y = __shfl_up(sv, d);
            if (lane >= d) sv += y;
        }
        if (lane < 16) wsum[lane] = sv;
    }
    __syncthreads();
    int woff = (wid > 0) ? wsum[wid - 1] : 0;
    if (i < N_NODES) offs[i] = woff + xinc - v;   // tile-local exclusive
    if (threadIdx.x == 0) parts[blockIdx.x] = wsum[15];
}

// each block sums parts[0..bid-1] itself (fuses scan_tops + scan_add)
__global__ __launch_bounds__(1024) void scan_add_kernel(
    int* __restrict__ offs, const int* __restrict__ parts)
{
    __shared__ int pre_s;
    if (threadIdx.x < 64) {
        int v = ((int)threadIdx.x < (int)blockIdx.x) ? parts[threadIdx.x] : 0;
        #pragma unroll
        for (int off = 32; off >= 1; off >>= 1) v += __shfl_xor(v, off);
        if (threadIdx.x == 0) pre_s = v;
    }
    __syncthreads();
    int i = blockIdx.x * 1024 + threadIdx.x;
    if (i < N_NODES) offs[i] += pre_s;
}

// fill: NO atomics — rank precomputed in gemm_count
__global__ void fill_kernel(const int* __restrict__ srcs, const int* __restrict__ dsts,
                            const int* __restrict__ etype, const int* __restrict__ rank,
                            const int* __restrict__ offs, unsigned int* __restrict__ epack)
{
    int e = blockIdx.x * 256 + threadIdx.x;
    if (e < N_EDGES) {
        int d = dsts[e];
        int p = offs[d] + rank[e];
        epack[p] = (unsigned int)srcs[e] | ((unsigned int)etype[e] << 16);
    }
}

// ---------------- K5: fused softmax+aggregate+residual+LayerNorm ----------
__global__ __launch_bounds__(256) void aggregate_kernel(
    const unsigned short* __restrict__ hb, const float* __restrict__ alpha_src,
    const float* __restrict__ alpha_dst, const float* __restrict__ etab,
    const unsigned int* __restrict__ epack, const int* __restrict__ offs,
    const float* __restrict__ gamma, const float* __restrict__ beta,
    float* __restrict__ out)
{
    int lane = threadIdx.x & 63;
    int wid  = threadIdx.x >> 6;
    int half = lane >> 5;              // two nodes per wave
    int l5   = lane & 31;
    int n = blockIdx.x * 8 + wid * 2 + half;
    if (n >= N_NODES) return;

    int e0 = offs[n];                         // exclusive scan
    int e1 = (n == N_NODES - 1) ? N_EDGES : offs[n + 1];
    int dg = e1 - e0;

    int g  = l5 >> 3;            // edge group 0..3 (stride-4 over edges)
    int sl = l5 & 7;             // dims sl*16 .. sl*16+15
    int headL = sl >> 1;

    float ad_h = alpha_dst[(size_t)n * 4 + headL];
    float et0 = etab[0 * 4 + headL];
    float et1 = etab[1 * 4 + headL];
    float et2 = etab[2 * 4 + headL];

    float s = 0.f;
    float acc[16];
    #pragma unroll
    for (int k = 0; k < 16; ++k) acc[k] = 0.f;

    const unsigned int* ep = epack + e0;
    for (int j = g; j < dg; j += 4) {
        unsigned int p = ep[j];
        int si = p & 0xFFFF;
        int t  = p >> 16;
        float asv = alpha_src[(size_t)si * 4 + headL];
        const uint4* hp = (const uint4*)(hb + ((size_t)si << 7) + (sl << 4));
        uint4 hA = hp[0];
        uint4 hB = hp[1];
        float ev = (t == 0) ? et0 : ((t == 1) ? et1 : et2);
        float c = LRELU(asv + ad_h + ev);
        float w = __expf(c);
        s += w;
        acc[0]  += w * BFLO(hA.x); acc[1]  += w * BFHI(hA.x);
        acc[2]  += w * BFLO(hA.y); acc[3]  += w * BFHI(hA.y);
        acc[4]  += w * BFLO(hA.z); acc[5]  += w * BFHI(hA.z);
        acc[6]  += w * BFLO(hA.w); acc[7]  += w * BFHI(hA.w);
        acc[8]  += w * BFLO(hB.x); acc[9]  += w * BFHI(hB.x);
        acc[10] += w * BFLO(hB.y); acc[11] += w * BFHI(hB.y);
        acc[12] += w * BFLO(hB.z); acc[13] += w * BFHI(hB.z);
        acc[14] += w * BFLO(hB.w); acc[15] += w * BFHI(hB.w);
    }

    // combine the 4 edge-groups
    #pragma unroll
    for (int k = 0; k < 16; ++k) {
        acc[k] += __shfl_xor(acc[k], 8);
        acc[k] += __shfl_xor(acc[k], 16);
    }
    s += __shfl_xor(s, 8);
    s += __shfl_xor(s, 16);
    float rs = 1.0f / (s + 1e-10f);

    // ---- epilogue: normalize + residual + LayerNorm ----
    const uint4* rp = (const uint4*)(hb + ((size_t)n << 7) + (sl << 4));
    uint4 r0 = rp[0];
    uint4 r1 = rp[1];
    float o[16];
    o[0]  = acc[0]  * rs + BFLO(r0.x); o[1]  = acc[1]  * rs + BFHI(r0.x);
    o[2]  = acc[2]  * rs + BFLO(r0.y); o[3]  = acc[3]  * rs + BFHI(r0.y);
    o[4]  = acc[4]  * rs + BFLO(r0.z); o[5]  = acc[5]  * rs + BFHI(r0.z);
    o[6]  = acc[6]  * rs + BFLO(r0.w); o[7]  = acc[7]  * rs + BFHI(r0.w);
    o[8]  = acc[8]  * rs + BFLO(r1.x); o[9]  = acc[9]  * rs + BFHI(r1.x);
    o[10] = acc[10] * rs + BFLO(r1.y); o[11] = acc[11] * rs + BFHI(r1.y);
    o[12] = acc[12] * rs + BFLO(r1.z); o[13] = acc[13] * rs + BFHI(r1.z);
    o[14] = acc[14] * rs + BFLO(r1.w); o[15] = acc[15] * rs + BFHI(r1.w);

    float lsum = 0.f;
    #pragma unroll
    for (int k = 0; k < 16; ++k) lsum += o[k];
    #pragma unroll
    for (int off = 4; off >= 1; off >>= 1) lsum += __shfl_xor(lsum, off);
    float mean = lsum * (1.0f / 128.0f);
    float vs = 0.f;
    #pragma unroll
    for (int k = 0; k < 16; ++k) { float d = o[k] - mean; vs += d * d; }
    #pragma unroll
    for (int off = 4; off >= 1; off >>= 1) vs += __shfl_xor(vs, off);
    float inv = rsqrtf(vs * (1.0f / 128.0f) + LN_EPS);

    float4 gv = *(const float4*)(gamma + sl * 16 + g * 4);
    float4 bv = *(const float4*)(beta  + sl * 16 + g * 4);
    float4 wv;
    wv.x = (o[g * 4 + 0] - mean) * inv * gv.x + bv.x;
    wv.y = (o[g * 4 + 1] - mean) * inv * gv.y + bv.y;
    wv.z = (o[g * 4 + 2] - mean) * inv * gv.z + bv.z;
    wv.w = (o[g * 4 + 3] - mean) * inv * gv.w + bv.w;
    *(float4*)(out + (size_t)n * OUT_DIM + sl * 16 + g * 4) = wv;
}

// ---------------------------------------------------------------------------
extern "C" void kernel_launch(void* const* d_in, const int* in_sizes, int n_in,
                              void* d_out, int out_size, void* d_ws, size_t ws_size,
                              hipStream_t stream)
{
    const float* x          = (const float*)d_in[0];
    const int*   edge_index = (const int*)d_in[1];
    const int*   etype      = (const int*)d_in[2];
    const float* W          = (const float*)d_in[3];
    const float* a_src      = (const float*)d_in[4];
    const float* a_dst      = (const float*)d_in[5];
    const float* a_edge     = (const float*)d_in[6];
    const float* edge_embed = (const float*)d_in[7];
    const float* gamma      = (const float*)d_in[8];
    const float* beta       = (const float*)d_in[9];

    float* ws = (float*)d_ws;
    unsigned short* hb = (unsigned short*)(ws + WS_HB);
    float* asrc = ws + WS_ASRC;
    float* adst = ws + WS_ADST;
    float* etab = ws + WS_ETAB;
    unsigned short* avtab = (unsigned short*)((int*)d_ws + WS_AVTAB);
    int*   offs = (int*)d_ws + WS_OFFS;
    int*   parts= (int*)d_ws + WS_PARTS;
    unsigned int* epack = (unsigned int*)d_ws + WS_EPACK;
    int*   rank = (int*)d_ws + WS_RANK;
    int*   degp = (int*)d_ws + WS_DEGP;

    const int* srcs = edge_index;
    const int* dsts = edge_index + N_EDGES;

    prep_zero_kernel<<<PREP_BLOCKS, 256, 0, stream>>>(
        (int4*)degp, W, a_src, a_dst, edge_embed, a_edge, etab, avtab);
    gemm_count_kernel<<<GEMM_BLOCKS + COUNT_BLOCKS, 256, 0, stream>>>(
        x, W, avtab, hb, asrc, adst, dsts, degp, rank);
    scan_part_kernel<<<SCAN_BLOCKS, 1024, 0, stream>>>(degp, offs, parts);
    scan_add_kernel<<<SCAN_BLOCKS, 1024, 0, stream>>>(offs, parts);
    fill_kernel<<<(N_EDGES + 255) / 256, 256, 0, stream>>>(srcs, dsts, etype, rank, offs, epack);
    aggregate_kernel<<<(N_NODES + 7) / 8, 256, 0, stream>>>(
        hb, asrc, adst, etab, epack, offs, gamma, beta, (float*)d_out);
}